// Round 1
// baseline (437.843 us; speedup 1.0000x reference)
//
#include <hip/hip_runtime.h>
#include <math.h>

// Problem constants (fixed shapes from reference)
#define B_   64
#define T_   2048
#define ENC_ 512
#define U_   128
#define NC   16      // K chunks of 32
#define MBLK 128

typedef __attribute__((ext_vector_type(8))) _Float16 half8;
typedef __attribute__((ext_vector_type(4))) float float4v;

// async global->LDS, 16 B per lane. LDS dest = wave-uniform base + lane*16.
__device__ __forceinline__ void async_ld16(const void* g, void* l) {
    __builtin_amdgcn_global_load_lds(
        (const __attribute__((address_space(1))) void*)g,
        (__attribute__((address_space(3))) void*)l, 16, 0, 0);
}

// split x into hi (RTN fp16) + lo (fp16 of remainder): combined err ~2^-22|x|
__device__ inline void cvt_split8_f16(const float4 a0, const float4 a1,
                                      half8& h, half8& l) {
    const float xs[8] = {a0.x, a0.y, a0.z, a0.w, a1.x, a1.y, a1.z, a1.w};
#pragma unroll
    for (int j = 0; j < 8; ++j) {
        const _Float16 hi = (_Float16)xs[j];
        h[j] = hi;
        l[j] = (_Float16)(xs[j] - (float)hi);
    }
}

// tanh via single v_exp: 1 - 2/(e^{2x}+1); exact at ±inf, err ~1e-6
__device__ inline float fast_tanh(float x) {
    const float e = __expf(2.0f * x);
    return 1.0f - 2.0f / (e + 1.0f);
}

// ---------------------------------------------------------------------------
// Prep kernel (merged): blocks 0..63 qproj; 64..95 wprep; 96..224 zero.
//  qproj: q'[b][u] = dh[b,:]@Wa[:,u] + ba[u] + bb[u]  (bb folded; bv cancels)
//  wprep: Wb -> MFMA B-frag order, single fp16 (RTN).
//         B-frag (16x16x32): lane L holds B[k=(L>>4)*8+j][n=(L&15)].
//         frag f = c*8+gn; whf[(f*64+L)*8+j]; chunk c = contiguous 8 KB.
//  zero:  uctx (32768) + Zsum (64)
// ---------------------------------------------------------------------------
__global__ __launch_bounds__(256)
void prep_kernel(const float* __restrict__ dh,
                 const float* __restrict__ Wa,
                 const float* __restrict__ ba,
                 const float* __restrict__ bb,
                 const float* __restrict__ Wb,
                 float* __restrict__ q,
                 _Float16* __restrict__ whf,
                 float* __restrict__ uz) {
    const int blk = blockIdx.x;
    const int tid = threadIdx.x;
    if (blk < 64) {
        if (tid < U_) {
            const int b = blk, u = tid;
            const float* dhb = dh + b * ENC_;
            float a0 = 0.f, a1 = 0.f, a2 = 0.f, a3 = 0.f;
#pragma unroll 4
            for (int e = 0; e < ENC_; e += 4) {
                a0 += dhb[e + 0] * Wa[(e + 0) * U_ + u];
                a1 += dhb[e + 1] * Wa[(e + 1) * U_ + u];
                a2 += dhb[e + 2] * Wa[(e + 2) * U_ + u];
                a3 += dhb[e + 3] * Wa[(e + 3) * U_ + u];
            }
            q[b * U_ + u] = ((a0 + a1) + (a2 + a3)) + ba[u] + bb[u];
        }
    } else if (blk < 96) {
        const int fid = (blk - 64) * 4 + (tid >> 6);   // 0..127
        const int c   = fid >> 3;
        const int gn  = fid & 7;
        const int L   = tid & 63;
        const int n   = gn * 16 + (L & 15);
        const int k0  = c * 32 + (L >> 4) * 8;
        half8 hi;
#pragma unroll
        for (int j = 0; j < 8; ++j)
            hi[j] = (_Float16)Wb[(size_t)(k0 + j) * U_ + n];
        *(half8*)(whf + ((size_t)fid * 64 + L) * 8) = hi;
    } else {
        const int i = (blk - 96) * 256 + tid;
        if (i < B_ * ENC_ + B_) uz[i] = 0.f;
    }
}

// ---------------------------------------------------------------------------
// Kernel B v2: fused score GEMM + exp + unnormalized context.
// 128 rows/block, 4 waves, wave tile 32 rows x 128 U (no wc split ->
// no duplicated A conversion, no cross-wave sred reduce).
// Staging entirely via global_load_lds(16B):
//   A: raw fp32, XOR-swizzled on the GLOBAL SOURCE side (linear LDS dest,
//      swizzled read) so per-row ds_read_b128 is bank-conflict-free.
//      Element (row,k) lives at float idx row*32 + (k ^ ((row&7)*4)).
//   B: pre-converted fp16 frags, linear copy (layout already lane-linear).
// hi/lo split conversion happens at fragment-read time (each element
// converted exactly once per block). No register prefetch, no LDS-write
// instructions -> ~145 VGPR, no spills, async loads in flight across the
// whole compute phase (drained by the compiler's vmcnt(0) at the barrier).
// LDS: A 2x16KB + B 2x8KB + ew = 48.5 KB -> 3 blocks/CU.
// Epilogue: tanh*Wv dot over all 128 u in-wave (shfl over lanes&15),
// e=exp(s) (no max-sub: |s| <= ||Wv||_1 ~ 11, fp32-safe).
// Phase 2: block's 128 enc rows (L2-hot) -> atomicAdd unnorm context.
// ---------------------------------------------------------------------------
__global__ __launch_bounds__(256, 3)
void score_ctx_kernel(const float* __restrict__ enc,
                      const _Float16* __restrict__ whf,
                      const float* __restrict__ q,
                      const float* __restrict__ Wv,
                      float* __restrict__ expw,
                      float* __restrict__ uctx,
                      float* __restrict__ Zsum) {
    __shared__ __align__(16) float    As[2][4096];   // 16 KB per buffer
    __shared__ __align__(16) _Float16 Bs[2][4096];   // 8 KB per buffer
    __shared__ float ew[MBLK];

    const int tid = threadIdx.x;
    const int w   = tid >> 6;       // wave 0..3
    const int L   = tid & 63;
    const int m0  = blockIdx.x * MBLK;
    const int b   = m0 >> 11;       // blocks never straddle a batch

    // ---- staging address setup ----
    // A: dest byte (in chunk) = w*4096 + j*1024 + L*16
    //    -> row = w*32 + j*8 + (L>>3); dest k-slot = (L&7)*4 floats.
    //    source k = dest-slot ^ ((row&7)*4); row&7 == L>>3 for all j.
    const int arow = w * 32 + (L >> 3);
    const int akf  = ((L & 7) ^ (L >> 3)) * 4;
    const float* aprow = enc + (size_t)(m0 + arow) * ENC_ + akf;
    // B: linear, src halfs = c*4096 + w*1024 + j*512 + L*8
    const _Float16* bprow = whf + w * 1024 + L * 8;

    float4v acc[2][8];
#pragma unroll
    for (int mi = 0; mi < 2; ++mi)
#pragma unroll
        for (int gi = 0; gi < 8; ++gi) acc[mi][gi] = (float4v)0.f;

    // ---- prologue: stage chunk 0 ----
    {
#pragma unroll
        for (int j = 0; j < 4; ++j)
            async_ld16(aprow + (size_t)j * 8 * ENC_, &As[0][w * 1024 + j * 256]);
#pragma unroll
        for (int j = 0; j < 2; ++j)
            async_ld16(bprow + j * 512, &Bs[0][w * 1024 + j * 512]);
    }
    __syncthreads();   // compiler drains vmcnt(0) before s_barrier

    for (int c = 0; c < NC; ++c) {
        const int cur = c & 1;

        // ---- issue async stage of chunk c+1 into the other buffer ----
        if (c < NC - 1) {
            const int nxt = cur ^ 1;
            const float* ap = aprow + (c + 1) * 32;
#pragma unroll
            for (int j = 0; j < 4; ++j)
                async_ld16(ap + (size_t)j * 8 * ENC_, &As[nxt][w * 1024 + j * 256]);
            const _Float16* bp = bprow + (size_t)(c + 1) * 4096;
#pragma unroll
            for (int j = 0; j < 2; ++j)
                async_ld16(bp + j * 512, &Bs[nxt][w * 1024 + j * 512]);
        }

        // ---- B frags: lane-linear 16 B/lane, conflict-free ----
        half8 bh[8];
#pragma unroll
        for (int gi = 0; gi < 8; ++gi)
            bh[gi] = *(const half8*)(&Bs[cur][(gi * 64 + L) * 8]);

        // ---- A frags: swizzled fp32 read + split conversion ----
        half8 ah[2], al[2];
#pragma unroll
        for (int mi = 0; mi < 2; ++mi) {
            const int row = w * 32 + mi * 16 + (L & 15);
            const int s4  = (row & 7) * 4;
            const int k0  = (L >> 4) * 8;
            const float4 x0 = *(const float4*)(&As[cur][row * 32 + (k0 ^ s4)]);
            const float4 x1 = *(const float4*)(&As[cur][row * 32 + ((k0 + 4) ^ s4)]);
            cvt_split8_f16(x0, x1, ah[mi], al[mi]);
        }

        // ---- 32 MFMAs (hi+lo per 16x16 tile) ----
#pragma unroll
        for (int mi = 0; mi < 2; ++mi)
#pragma unroll
            for (int gi = 0; gi < 8; ++gi) {
                acc[mi][gi] = __builtin_amdgcn_mfma_f32_16x16x32_f16(ah[mi], bh[gi], acc[mi][gi], 0, 0, 0);
                acc[mi][gi] = __builtin_amdgcn_mfma_f32_16x16x32_f16(al[mi], bh[gi], acc[mi][gi], 0, 0, 0);
            }

        __syncthreads();   // drains async stage; next buffer ready
    }

    // ---- epilogue: tanh + Wv dot over all 128 u (in-wave) ----
    // C/D layout: col(u) = L&15 (+gi*16), row = (L>>4)*4 + reg
    const int n15 = L & 15;
    float qv[8], wvv[8];
#pragma unroll
    for (int gi = 0; gi < 8; ++gi) {
        const int u = gi * 16 + n15;
        qv[gi]  = q[b * U_ + u];
        wvv[gi] = Wv[u];
    }
#pragma unroll
    for (int mi = 0; mi < 2; ++mi) {
#pragma unroll
        for (int r = 0; r < 4; ++r) {
            float s = 0.f;
#pragma unroll
            for (int gi = 0; gi < 8; ++gi)
                s += fast_tanh(qv[gi] + acc[mi][gi][r]) * wvv[gi];
            s += __shfl_xor(s, 1, 64);
            s += __shfl_xor(s, 2, 64);
            s += __shfl_xor(s, 4, 64);
            s += __shfl_xor(s, 8, 64);
            if (n15 == 0) {
                const int mrow = w * 32 + mi * 16 + (L >> 4) * 4 + r;
                const float e = __expf(s);
                ew[mrow] = e;
                expw[m0 + mrow] = e;
            }
        }
    }
    __syncthreads();

    // ---- phase 2: unnormalized context over this block's 128 rows ----
    const int col = tid * 2;
    const float* ebase = enc + (size_t)m0 * ENC_ + col;
    float sx = 0.f, sy = 0.f;
#pragma unroll 8
    for (int t = 0; t < MBLK; ++t) {
        const float wgt = ew[t];                       // LDS broadcast
        const float2 v = *(const float2*)(ebase + (size_t)t * ENC_);
        sx += wgt * v.x;
        sy += wgt * v.y;
    }
    atomicAdd(&uctx[b * ENC_ + col], sx);
    atomicAdd(&uctx[b * ENC_ + col + 1], sy);

    if (tid < 64) {
        float z = ew[tid] + ew[tid + 64];
        z += __shfl_xor(z, 1, 64);
        z += __shfl_xor(z, 2, 64);
        z += __shfl_xor(z, 4, 64);
        z += __shfl_xor(z, 8, 64);
        z += __shfl_xor(z, 16, 64);
        z += __shfl_xor(z, 32, 64);
        if (tid == 0) atomicAdd(&Zsum[b], z);
    }
}

// ---------------------------------------------------------------------------
// Kernel N: normalize — ctx = uctx/Z, attn = expw/Z.
// ---------------------------------------------------------------------------
__global__ void normalize_kernel(const float* __restrict__ uctx,
                                 const float* __restrict__ Zsum,
                                 const float* __restrict__ expw,
                                 float* __restrict__ ctx,
                                 float* __restrict__ attn) {
    const int idx = blockIdx.x * 256 + threadIdx.x;
    if (idx < B_ * ENC_) {
        ctx[idx] = uctx[idx] / Zsum[idx >> 9];        // ENC_ = 512
    } else {
        const int i2 = idx - B_ * ENC_;
        attn[i2] = expw[i2] / Zsum[i2 >> 11];         // T_ = 2048
    }
}

// ---------------------------------------------------------------------------
extern "C" void kernel_launch(void* const* d_in, const int* in_sizes, int n_in,
                              void* d_out, int out_size, void* d_ws, size_t ws_size,
                              hipStream_t stream) {
    const float* dh  = (const float*)d_in[0];  // [64,512]
    const float* enc = (const float*)d_in[1];  // [64,2048,512]
    const float* Wa  = (const float*)d_in[2];  // [512,128]
    const float* ba  = (const float*)d_in[3];  // [128]
    const float* Wb  = (const float*)d_in[4];  // [512,128]
    const float* bb  = (const float*)d_in[5];  // [128]
    const float* Wv  = (const float*)d_in[6];  // [128,1]
    // d_in[7] = bv — cancels in softmax, unused.

    float* out      = (float*)d_out;
    float* ctx      = out;                 // [64,512]
    float* attn_out = out + (B_ * ENC_);   // [64,2048]

    float* ws   = (float*)d_ws;
    float* q    = ws;                              // 8192
    float* expw = ws + 8192;                       // 131072
    float* uctx = ws + 8192 + B_ * T_;             // 32768
    float* Zs   = uctx + B_ * ENC_;                // 64
    _Float16* whf = (_Float16*)(Zs + 64);          // 65536 halfs (128 KB)

    prep_kernel<<<225, 256, 0, stream>>>(dh, Wa, ba, bb, Wb, q, whf, uctx);
    score_ctx_kernel<<<(B_ * T_) / MBLK, 256, 0, stream>>>(enc, whf, q, Wv,
                                                           expw, uctx, Zs);
    normalize_kernel<<<(B_ * (ENC_ + T_)) / 256, 256, 0, stream>>>(uctx, Zs, expw,
                                                                   ctx, attn_out);
}

// Round 2
// 431.122 us; speedup vs baseline: 1.0156x; 1.0156x over previous
//
#include <hip/hip_runtime.h>
#include <math.h>

// Problem constants (fixed shapes from reference)
#define B_   64
#define T_   2048
#define ENC_ 512
#define U_   128
#define NC   16      // K chunks of 32
#define MBLK 128

typedef __attribute__((ext_vector_type(8))) _Float16 half8;
typedef __attribute__((ext_vector_type(4))) float float4v;

// async global->LDS, 16 B per lane. LDS dest = wave-uniform base + lane*16.
__device__ __forceinline__ void async_ld16(const void* g, void* l) {
    __builtin_amdgcn_global_load_lds(
        (const __attribute__((address_space(1))) void*)g,
        (__attribute__((address_space(3))) void*)l, 16, 0, 0);
}

// split x into hi (RTN fp16) + lo (fp16 of remainder): combined err ~2^-22|x|
__device__ inline void cvt_split8_f16(const float4 a0, const float4 a1,
                                      half8& h, half8& l) {
    const float xs[8] = {a0.x, a0.y, a0.z, a0.w, a1.x, a1.y, a1.z, a1.w};
#pragma unroll
    for (int j = 0; j < 8; ++j) {
        const _Float16 hi = (_Float16)xs[j];
        h[j] = hi;
        l[j] = (_Float16)(xs[j] - (float)hi);
    }
}

// tanh via single v_exp: 1 - 2/(e^{2x}+1); exact at ±inf, err ~1e-6
__device__ inline float fast_tanh(float x) {
    const float e = __expf(2.0f * x);
    return 1.0f - 2.0f / (e + 1.0f);
}

// ---------------------------------------------------------------------------
// Prep kernel (merged): blocks 0..63 qproj; 64..95 wprep; 96..224 zero.
//  qproj: q'[b][u] = dh[b,:]@Wa[:,u] + ba[u] + bb[u]  (bb folded; bv cancels)
//  wprep: Wb -> MFMA B-frag order, single fp16 (RTN).
//         B-frag (16x16x32): lane L holds B[k=(L>>4)*8+j][n=(L&15)].
//         frag f = c*8+gn; whf[(f*64+L)*8+j]; chunk c = contiguous 8 KB.
//  zero:  uctx (32768) + Zsum (64)
// ---------------------------------------------------------------------------
__global__ __launch_bounds__(256)
void prep_kernel(const float* __restrict__ dh,
                 const float* __restrict__ Wa,
                 const float* __restrict__ ba,
                 const float* __restrict__ bb,
                 const float* __restrict__ Wb,
                 float* __restrict__ q,
                 _Float16* __restrict__ whf,
                 float* __restrict__ uz) {
    const int blk = blockIdx.x;
    const int tid = threadIdx.x;
    if (blk < 64) {
        if (tid < U_) {
            const int b = blk, u = tid;
            const float* dhb = dh + b * ENC_;
            float a0 = 0.f, a1 = 0.f, a2 = 0.f, a3 = 0.f;
#pragma unroll 4
            for (int e = 0; e < ENC_; e += 4) {
                a0 += dhb[e + 0] * Wa[(e + 0) * U_ + u];
                a1 += dhb[e + 1] * Wa[(e + 1) * U_ + u];
                a2 += dhb[e + 2] * Wa[(e + 2) * U_ + u];
                a3 += dhb[e + 3] * Wa[(e + 3) * U_ + u];
            }
            q[b * U_ + u] = ((a0 + a1) + (a2 + a3)) + ba[u] + bb[u];
        }
    } else if (blk < 96) {
        const int fid = (blk - 64) * 4 + (tid >> 6);   // 0..127
        const int c   = fid >> 3;
        const int gn  = fid & 7;
        const int L   = tid & 63;
        const int n   = gn * 16 + (L & 15);
        const int k0  = c * 32 + (L >> 4) * 8;
        half8 hi;
#pragma unroll
        for (int j = 0; j < 8; ++j)
            hi[j] = (_Float16)Wb[(size_t)(k0 + j) * U_ + n];
        *(half8*)(whf + ((size_t)fid * 64 + L) * 8) = hi;
    } else {
        const int i = (blk - 96) * 256 + tid;
        if (i < B_ * ENC_ + B_) uz[i] = 0.f;
    }
}

// ---------------------------------------------------------------------------
// Kernel B v3: fused score GEMM + exp + unnormalized context.
// BARRIER-FREE K-loop with counted vmcnt (T4):
//   A: wave-LOCAL staging (wave w stages & reads rows w*32..w*32+31) via
//      global_load_lds(16B), fp32, source-side XOR swizzle (linear LDS dest,
//      swizzled read) -> conflict-free ds_read_b128. Double-buffered.
//      No cross-wave LDS dependency => NO __syncthreads in the loop.
//   B: read straight from global whf (128 KB, L2-resident) into registers
//      each chunk; no LDS, no staging.
// Per chunk per wave: issue 8 B-loads, then 4 A-lds-loads for c+1, then
// s_waitcnt vmcnt(12) — retires only A(c), leaves B(c)+A(c+1) in flight.
// Compiler's own minimal wait (vmcnt(4)) covers B before the MFMAs.
// NOTHING drains to vmcnt(0) inside the loop. Last chunk peeled (vmcnt(8)).
// LDS: A 2x16KB + ew = 32.5 KB; ~145 VGPR -> 3 blocks/CU.
// Epilogue: tanh*Wv dot over all 128 u in-wave, e=exp(s) (no max-sub:
// |s| <= ||Wv||_1 ~ 11, fp32-safe). One __syncthreads before phase 2.
// Phase 2: block's 128 enc rows (L2-hot) -> atomicAdd unnorm context.
// ---------------------------------------------------------------------------
__global__ __launch_bounds__(256, 3)
void score_ctx_kernel(const float* __restrict__ enc,
                      const _Float16* __restrict__ whf,
                      const float* __restrict__ q,
                      const float* __restrict__ Wv,
                      float* __restrict__ expw,
                      float* __restrict__ uctx,
                      float* __restrict__ Zsum) {
    __shared__ __align__(16) float As[2][4096];   // 16 KB per buffer
    __shared__ float ew[MBLK];

    const int tid = threadIdx.x;
    const int w   = tid >> 6;       // wave 0..3
    const int L   = tid & 63;
    const int m0  = blockIdx.x * MBLK;
    const int b   = m0 >> 11;       // blocks never straddle a batch

    // ---- staging address setup ----
    // A: dest byte (in chunk) = w*4096 + j*1024 + L*16
    //    -> row = w*32 + j*8 + (L>>3); dest k-slot = (L&7)*4 floats.
    //    source k = dest-slot ^ ((row&7)*4); row&7 == L>>3 for all j.
    const int arow = w * 32 + (L >> 3);
    const int akf  = ((L & 7) ^ (L >> 3)) * 4;
    const float* aprow = enc + (size_t)(m0 + arow) * ENC_ + akf;

    float4v acc[2][8];
#pragma unroll
    for (int mi = 0; mi < 2; ++mi)
#pragma unroll
        for (int gi = 0; gi < 8; ++gi) acc[mi][gi] = (float4v)0.f;

    // ---- prologue: stage A chunk 0 (wave-local; no barrier needed) ----
#pragma unroll
    for (int j = 0; j < 4; ++j)
        async_ld16(aprow + (size_t)j * 8 * ENC_, &As[0][w * 1024 + j * 256]);

    for (int c = 0; c < NC - 1; ++c) {
        const int cur = c & 1;
        const int nxt = cur ^ 1;

        // ---- B frags for chunk c: global (L2-hot), lane-linear 16 B ----
        half8 bh[8];
        const _Float16* bp = whf + (size_t)c * 4096 + L * 8;
#pragma unroll
        for (int gi = 0; gi < 8; ++gi)
            bh[gi] = *(const half8*)(bp + gi * 512);

        // ---- issue A stage for chunk c+1 (after B so B-wait stays small).
        // lgkmcnt(0): prior-iteration ds_reads of buf[nxt] are retired
        // before we overwrite it (WAR close-out; effectively free).
        asm volatile("s_waitcnt lgkmcnt(0)" ::: "memory");
        const float* ap = aprow + (c + 1) * 32;
#pragma unroll
        for (int j = 0; j < 4; ++j)
            async_ld16(ap + (size_t)j * 8 * ENC_, &As[nxt][w * 1024 + j * 256]);

        // ---- counted wait: retire A(c) only; B(c)=8 + A(c+1)=4 stay ----
        asm volatile("s_waitcnt vmcnt(12)" ::: "memory");

        // ---- A frags: swizzled fp32 LDS read + split conversion ----
        half8 ah[2], al[2];
#pragma unroll
        for (int mi = 0; mi < 2; ++mi) {
            const int row = w * 32 + mi * 16 + (L & 15);
            const int s4  = (row & 7) * 4;
            const int k0  = (L >> 4) * 8;
            const float4 x0 = *(const float4*)(&As[cur][row * 32 + (k0 ^ s4)]);
            const float4 x1 = *(const float4*)(&As[cur][row * 32 + ((k0 + 4) ^ s4)]);
            cvt_split8_f16(x0, x1, ah[mi], al[mi]);
        }

        // ---- 32 MFMAs (hi+lo per 16x16 tile) ----
#pragma unroll
        for (int mi = 0; mi < 2; ++mi)
#pragma unroll
            for (int gi = 0; gi < 8; ++gi) {
                acc[mi][gi] = __builtin_amdgcn_mfma_f32_16x16x32_f16(ah[mi], bh[gi], acc[mi][gi], 0, 0, 0);
                acc[mi][gi] = __builtin_amdgcn_mfma_f32_16x16x32_f16(al[mi], bh[gi], acc[mi][gi], 0, 0, 0);
            }
    }

    // ---- peeled last chunk (c = NC-1): no new A issue -> vmcnt(8) ----
    {
        const int c   = NC - 1;
        const int cur = c & 1;
        half8 bh[8];
        const _Float16* bp = whf + (size_t)c * 4096 + L * 8;
#pragma unroll
        for (int gi = 0; gi < 8; ++gi)
            bh[gi] = *(const half8*)(bp + gi * 512);

        // outstanding = A(15)=4 (oldest) + B(15)=8 -> wait to <=8 retires A(15)
        asm volatile("s_waitcnt vmcnt(8)" ::: "memory");

        half8 ah[2], al[2];
#pragma unroll
        for (int mi = 0; mi < 2; ++mi) {
            const int row = w * 32 + mi * 16 + (L & 15);
            const int s4  = (row & 7) * 4;
            const int k0  = (L >> 4) * 8;
            const float4 x0 = *(const float4*)(&As[cur][row * 32 + (k0 ^ s4)]);
            const float4 x1 = *(const float4*)(&As[cur][row * 32 + ((k0 + 4) ^ s4)]);
            cvt_split8_f16(x0, x1, ah[mi], al[mi]);
        }
#pragma unroll
        for (int mi = 0; mi < 2; ++mi)
#pragma unroll
            for (int gi = 0; gi < 8; ++gi) {
                acc[mi][gi] = __builtin_amdgcn_mfma_f32_16x16x32_f16(ah[mi], bh[gi], acc[mi][gi], 0, 0, 0);
                acc[mi][gi] = __builtin_amdgcn_mfma_f32_16x16x32_f16(al[mi], bh[gi], acc[mi][gi], 0, 0, 0);
            }
    }

    // ---- epilogue: tanh + Wv dot over all 128 u (in-wave) ----
    // C/D layout: col(u) = L&15 (+gi*16), row = (L>>4)*4 + reg
    const int n15 = L & 15;
    float qv[8], wvv[8];
#pragma unroll
    for (int gi = 0; gi < 8; ++gi) {
        const int u = gi * 16 + n15;
        qv[gi]  = q[b * U_ + u];
        wvv[gi] = Wv[u];
    }
#pragma unroll
    for (int mi = 0; mi < 2; ++mi) {
#pragma unroll
        for (int r = 0; r < 4; ++r) {
            float s = 0.f;
#pragma unroll
            for (int gi = 0; gi < 8; ++gi)
                s += fast_tanh(qv[gi] + acc[mi][gi][r]) * wvv[gi];
            s += __shfl_xor(s, 1, 64);
            s += __shfl_xor(s, 2, 64);
            s += __shfl_xor(s, 4, 64);
            s += __shfl_xor(s, 8, 64);
            if (n15 == 0) {
                const int mrow = w * 32 + mi * 16 + (L >> 4) * 4 + r;
                const float e = __expf(s);
                ew[mrow] = e;
                expw[m0 + mrow] = e;
            }
        }
    }
    __syncthreads();

    // ---- phase 2: unnormalized context over this block's 128 rows ----
    const int col = tid * 2;
    const float* ebase = enc + (size_t)m0 * ENC_ + col;
    float sx = 0.f, sy = 0.f;
#pragma unroll 8
    for (int t = 0; t < MBLK; ++t) {
        const float wgt = ew[t];                       // LDS broadcast
        const float2 v = *(const float2*)(ebase + (size_t)t * ENC_);
        sx += wgt * v.x;
        sy += wgt * v.y;
    }
    atomicAdd(&uctx[b * ENC_ + col], sx);
    atomicAdd(&uctx[b * ENC_ + col + 1], sy);

    if (tid < 64) {
        float z = ew[tid] + ew[tid + 64];
        z += __shfl_xor(z, 1, 64);
        z += __shfl_xor(z, 2, 64);
        z += __shfl_xor(z, 4, 64);
        z += __shfl_xor(z, 8, 64);
        z += __shfl_xor(z, 16, 64);
        z += __shfl_xor(z, 32, 64);
        if (tid == 0) atomicAdd(&Zsum[b], z);
    }
}

// ---------------------------------------------------------------------------
// Kernel N: normalize — ctx = uctx/Z, attn = expw/Z.
// ---------------------------------------------------------------------------
__global__ void normalize_kernel(const float* __restrict__ uctx,
                                 const float* __restrict__ Zsum,
                                 const float* __restrict__ expw,
                                 float* __restrict__ ctx,
                                 float* __restrict__ attn) {
    const int idx = blockIdx.x * 256 + threadIdx.x;
    if (idx < B_ * ENC_) {
        ctx[idx] = uctx[idx] / Zsum[idx >> 9];        // ENC_ = 512
    } else {
        const int i2 = idx - B_ * ENC_;
        attn[i2] = expw[i2] / Zsum[i2 >> 11];         // T_ = 2048
    }
}

// ---------------------------------------------------------------------------
extern "C" void kernel_launch(void* const* d_in, const int* in_sizes, int n_in,
                              void* d_out, int out_size, void* d_ws, size_t ws_size,
                              hipStream_t stream) {
    const float* dh  = (const float*)d_in[0];  // [64,512]
    const float* enc = (const float*)d_in[1];  // [64,2048,512]
    const float* Wa  = (const float*)d_in[2];  // [512,128]
    const float* ba  = (const float*)d_in[3];  // [128]
    const float* Wb  = (const float*)d_in[4];  // [512,128]
    const float* bb  = (const float*)d_in[5];  // [128]
    const float* Wv  = (const float*)d_in[6];  // [128,1]
    // d_in[7] = bv — cancels in softmax, unused.

    float* out      = (float*)d_out;
    float* ctx      = out;                 // [64,512]
    float* attn_out = out + (B_ * ENC_);   // [64,2048]

    float* ws   = (float*)d_ws;
    float* q    = ws;                              // 8192
    float* expw = ws + 8192;                       // 131072
    float* uctx = ws + 8192 + B_ * T_;             // 32768
    float* Zs   = uctx + B_ * ENC_;                // 64
    _Float16* whf = (_Float16*)(Zs + 64);          // 65536 halfs (128 KB)

    prep_kernel<<<225, 256, 0, stream>>>(dh, Wa, ba, bb, Wb, q, whf, uctx);
    score_ctx_kernel<<<(B_ * T_) / MBLK, 256, 0, stream>>>(enc, whf, q, Wv,
                                                           expw, uctx, Zs);
    normalize_kernel<<<(B_ * (ENC_ + T_)) / 256, 256, 0, stream>>>(uctx, Zs, expw,
                                                                   ctx, attn_out);
}

// Round 3
// 427.474 us; speedup vs baseline: 1.0243x; 1.0085x over previous
//
#include <hip/hip_runtime.h>
#include <math.h>

// Problem constants (fixed shapes from reference)
#define B_   64
#define T_   2048
#define ENC_ 512
#define U_   128
#define NC   16      // K chunks of 32
#define MBLK 128
#define GSTRIDE 264  // floats per 8-row group: 256 data + 8 pad (bank-rotate)

typedef __attribute__((ext_vector_type(8))) _Float16 half8;
typedef __attribute__((ext_vector_type(4))) float float4v;

// async global->LDS, 16 B per lane. LDS dest = wave-uniform base + lane*16.
__device__ __forceinline__ void async_ld16(const void* g, void* l) {
    __builtin_amdgcn_global_load_lds(
        (const __attribute__((address_space(1))) void*)g,
        (__attribute__((address_space(3))) void*)l, 16, 0, 0);
}

// split x into hi (RTN fp16) + lo (fp16 of remainder): combined err ~2^-22|x|
__device__ inline void cvt_split8_f16(const float4 a0, const float4 a1,
                                      half8& h, half8& l) {
    const float xs[8] = {a0.x, a0.y, a0.z, a0.w, a1.x, a1.y, a1.z, a1.w};
#pragma unroll
    for (int j = 0; j < 8; ++j) {
        const _Float16 hi = (_Float16)xs[j];
        h[j] = hi;
        l[j] = (_Float16)(xs[j] - (float)hi);
    }
}

// tanh via single v_exp: 1 - 2/(e^{2x}+1); exact at ±inf, err ~1e-6
__device__ inline float fast_tanh(float x) {
    const float e = __expf(2.0f * x);
    return 1.0f - 2.0f / (e + 1.0f);
}

// ---------------------------------------------------------------------------
// Prep kernel (merged): blocks 0..63 qproj; 64..95 wprep; 96..224 zero.
//  qproj: q'[b][u] = dh[b,:]@Wa[:,u] + ba[u] + bb[u]  (bb folded; bv cancels)
//  wprep: Wb -> MFMA B-frag order, single fp16 (RTN).
//         B-frag (16x16x32): lane L holds B[k=(L>>4)*8+j][n=(L&15)].
//         frag f = c*8+gn; whf[(f*64+L)*8+j]; chunk c = contiguous 8 KB.
//  zero:  uctx (32768) + Zsum (64)
// ---------------------------------------------------------------------------
__global__ __launch_bounds__(256)
void prep_kernel(const float* __restrict__ dh,
                 const float* __restrict__ Wa,
                 const float* __restrict__ ba,
                 const float* __restrict__ bb,
                 const float* __restrict__ Wb,
                 float* __restrict__ q,
                 _Float16* __restrict__ whf,
                 float* __restrict__ uz) {
    const int blk = blockIdx.x;
    const int tid = threadIdx.x;
    if (blk < 64) {
        if (tid < U_) {
            const int b = blk, u = tid;
            const float* dhb = dh + b * ENC_;
            float a0 = 0.f, a1 = 0.f, a2 = 0.f, a3 = 0.f;
#pragma unroll 4
            for (int e = 0; e < ENC_; e += 4) {
                a0 += dhb[e + 0] * Wa[(e + 0) * U_ + u];
                a1 += dhb[e + 1] * Wa[(e + 1) * U_ + u];
                a2 += dhb[e + 2] * Wa[(e + 2) * U_ + u];
                a3 += dhb[e + 3] * Wa[(e + 3) * U_ + u];
            }
            q[b * U_ + u] = ((a0 + a1) + (a2 + a3)) + ba[u] + bb[u];
        }
    } else if (blk < 96) {
        const int fid = (blk - 64) * 4 + (tid >> 6);   // 0..127
        const int c   = fid >> 3;
        const int gn  = fid & 7;
        const int L   = tid & 63;
        const int n   = gn * 16 + (L & 15);
        const int k0  = c * 32 + (L >> 4) * 8;
        half8 hi;
#pragma unroll
        for (int j = 0; j < 8; ++j)
            hi[j] = (_Float16)Wb[(size_t)(k0 + j) * U_ + n];
        *(half8*)(whf + ((size_t)fid * 64 + L) * 8) = hi;
    } else {
        const int i = (blk - 96) * 256 + tid;
        if (i < B_ * ENC_ + B_) uz[i] = 0.f;
    }
}

// ---------------------------------------------------------------------------
// Kernel B v4: fused score GEMM + exp + unnormalized context.
// Latency-bound fix over v3 (which ran at 21% HBM, MfmaUtil 8%):
//  * A staged TWO chunks ahead via global_load_lds into 4 LDS buffers
//    (wave-local rows; no barriers). Wait-for-A trails issue by 2 full
//    iterations (~1000+ cyc > 900 cyc HBM latency).
//  * B register-prefetched ONE chunk ahead (pb -> bh). The compiler's
//    counted vmcnt before the copy waits for B(c) (issued a full
//    iteration earlier, covers L2 latency) and — since A(c) is OLDER
//    than B(c) in the VMEM queue — transitively retires A(c) too.
//    Explicit counted vmcnt(24/20/8) per unrolled iteration as a second
//    guarantee. Nothing drains to vmcnt(0) inside the loop.
//  * Bank-conflict fix (v3: 1.05M conflicts = +4 cyc per ds_read_b128):
//    8-row groups padded to 1056 B (GSTRIDE=264 floats) -> group bank
//    rotation (g%4)*8, on top of the row&7 XOR k-swizzle. Each bank is
//    touched exactly 8x per wave b128 read = hardware minimum.
//    Legal with global_load_lds: each load writes exactly one contiguous
//    1024 B group; pads sit BETWEEN loads.
// LDS: A 4x16.5KB + ew = 66.5 KB; combined regs ~200 -> 8 waves/CU.
// Epilogue: tanh*Wv dot over all 128 u in-wave, e=exp(s) (no max-sub:
// |s| <= ||Wv||_1 ~ 11, fp32-safe). One __syncthreads before phase 2.
// Phase 2: block's 128 enc rows (L2-hot) -> atomicAdd unnorm context.
// ---------------------------------------------------------------------------
__global__ __launch_bounds__(256, 2)
void score_ctx_kernel(const float* __restrict__ enc,
                      const _Float16* __restrict__ whf,
                      const float* __restrict__ q,
                      const float* __restrict__ Wv,
                      float* __restrict__ expw,
                      float* __restrict__ uctx,
                      float* __restrict__ Zsum) {
    __shared__ __align__(16) float As[4][16 * GSTRIDE];  // 4 x 16.5 KB
    __shared__ float ew[MBLK];

    const int tid = threadIdx.x;
    const int w   = tid >> 6;       // wave 0..3
    const int L   = tid & 63;
    const int m0  = blockIdx.x * MBLK;
    const int b   = m0 >> 11;       // blocks never straddle a batch

    // ---- staging address setup ----
    // Group g = row>>3 at float base g*GSTRIDE; within-group row rr=row&7 at
    // rr*32; k-group kg stored at slot (kg ^ rr). Store dest for async j is
    // wave-uniform &As[buf][(w*4+j)*GSTRIDE] (+lane*16B hardware scatter);
    // the XOR lives on the per-lane GLOBAL source address (akf).
    const int arow = w * 32 + (L >> 3);
    const int akf  = ((L & 7) ^ (L >> 3)) * 4;
    const float* aprow = enc + (size_t)(m0 + arow) * ENC_ + akf;

    float4v acc[2][8];
#pragma unroll
    for (int mi = 0; mi < 2; ++mi)
#pragma unroll
        for (int gi = 0; gi < 8; ++gi) acc[mi][gi] = (float4v)0.f;

    // ---- prologue: stage A(0), A(1); load pb = B(0) ----
#pragma unroll
    for (int j = 0; j < 4; ++j)
        async_ld16(aprow + (size_t)j * 8 * ENC_, &As[0][(w * 4 + j) * GSTRIDE]);
#pragma unroll
    for (int j = 0; j < 4; ++j)
        async_ld16(aprow + 32 + (size_t)j * 8 * ENC_, &As[1][(w * 4 + j) * GSTRIDE]);
    half8 pb[8];
    {
        const _Float16* bp = whf + L * 8;
#pragma unroll
        for (int gi = 0; gi < 8; ++gi) pb[gi] = *(const half8*)(bp + gi * 512);
    }

#pragma unroll
    for (int c = 0; c < NC; ++c) {
        // ---- B(c) regs (compiler inserts counted vmcnt for pb here) ----
        half8 bh[8];
#pragma unroll
        for (int gi = 0; gi < 8; ++gi) bh[gi] = pb[gi];

        // ---- issue B(c+1) register prefetch (L2-hot, 8 x b128) ----
        if (c + 1 < NC) {
            const _Float16* bp = whf + (size_t)(c + 1) * 4096 + L * 8;
#pragma unroll
            for (int gi = 0; gi < 8; ++gi) pb[gi] = *(const half8*)(bp + gi * 512);
        }

        // ---- issue A(c+2) stage (WAR on buf (c+2)&3 closed by lgkm) ----
        if (c + 2 < NC) {
            asm volatile("s_waitcnt lgkmcnt(0)" ::: "memory");
            const float* ap = aprow + (c + 2) * 32;
#pragma unroll
            for (int j = 0; j < 4; ++j)
                async_ld16(ap + (size_t)j * 8 * ENC_,
                           &As[(c + 2) & 3][(w * 4 + j) * GSTRIDE]);
        }

        // ---- counted wait: guarantee A(c) retired (usually a no-op) ----
        // ops issued after A(c): B(c)=8 + A(c+1)=4 + B(c+1)=8 + A(c+2)=4
        if (c < NC - 2)       asm volatile("s_waitcnt vmcnt(24)" ::: "memory");
        else if (c == NC - 2) asm volatile("s_waitcnt vmcnt(20)" ::: "memory");
        else                  asm volatile("s_waitcnt vmcnt(8)"  ::: "memory");

        // ---- A frags: swizzled fp32 LDS read + split conversion ----
        const float* Ab = &As[c & 3][0];
        half8 ah[2], al[2];
#pragma unroll
        for (int mi = 0; mi < 2; ++mi) {
            const int g  = w * 4 + mi * 2 + ((L >> 3) & 1);
            const int rr = L & 7;
            const int kg = (L >> 4) * 2;
            const float4 x0 = *(const float4*)(Ab + g * GSTRIDE + rr * 32 + ((kg ^ rr) * 4));
            const float4 x1 = *(const float4*)(Ab + g * GSTRIDE + rr * 32 + (((kg + 1) ^ rr) * 4));
            cvt_split8_f16(x0, x1, ah[mi], al[mi]);
        }

        // ---- 32 MFMAs (hi+lo per 16x16 tile) ----
#pragma unroll
        for (int mi = 0; mi < 2; ++mi)
#pragma unroll
            for (int gi = 0; gi < 8; ++gi) {
                acc[mi][gi] = __builtin_amdgcn_mfma_f32_16x16x32_f16(ah[mi], bh[gi], acc[mi][gi], 0, 0, 0);
                acc[mi][gi] = __builtin_amdgcn_mfma_f32_16x16x32_f16(al[mi], bh[gi], acc[mi][gi], 0, 0, 0);
            }
    }

    // ---- epilogue: tanh + Wv dot over all 128 u (in-wave) ----
    // C/D layout: col(u) = L&15 (+gi*16), row = (L>>4)*4 + reg
    const int n15 = L & 15;
    float qv[8], wvv[8];
#pragma unroll
    for (int gi = 0; gi < 8; ++gi) {
        const int u = gi * 16 + n15;
        qv[gi]  = q[b * U_ + u];
        wvv[gi] = Wv[u];
    }
#pragma unroll
    for (int mi = 0; mi < 2; ++mi) {
#pragma unroll
        for (int r = 0; r < 4; ++r) {
            float s = 0.f;
#pragma unroll
            for (int gi = 0; gi < 8; ++gi)
                s += fast_tanh(qv[gi] + acc[mi][gi][r]) * wvv[gi];
            s += __shfl_xor(s, 1, 64);
            s += __shfl_xor(s, 2, 64);
            s += __shfl_xor(s, 4, 64);
            s += __shfl_xor(s, 8, 64);
            if (n15 == 0) {
                const int mrow = w * 32 + mi * 16 + (L >> 4) * 4 + r;
                const float e = __expf(s);
                ew[mrow] = e;
                expw[m0 + mrow] = e;
            }
        }
    }
    __syncthreads();

    // ---- phase 2: unnormalized context over this block's 128 rows ----
    const int col = tid * 2;
    const float* ebase = enc + (size_t)m0 * ENC_ + col;
    float sx = 0.f, sy = 0.f;
#pragma unroll 8
    for (int t = 0; t < MBLK; ++t) {
        const float wgt = ew[t];                       // LDS broadcast
        const float2 v = *(const float2*)(ebase + (size_t)t * ENC_);
        sx += wgt * v.x;
        sy += wgt * v.y;
    }
    atomicAdd(&uctx[b * ENC_ + col], sx);
    atomicAdd(&uctx[b * ENC_ + col + 1], sy);

    if (tid < 64) {
        float z = ew[tid] + ew[tid + 64];
        z += __shfl_xor(z, 1, 64);
        z += __shfl_xor(z, 2, 64);
        z += __shfl_xor(z, 4, 64);
        z += __shfl_xor(z, 8, 64);
        z += __shfl_xor(z, 16, 64);
        z += __shfl_xor(z, 32, 64);
        if (tid == 0) atomicAdd(&Zsum[b], z);
    }
}

// ---------------------------------------------------------------------------
// Kernel N: normalize — ctx = uctx/Z, attn = expw/Z.
// ---------------------------------------------------------------------------
__global__ void normalize_kernel(const float* __restrict__ uctx,
                                 const float* __restrict__ Zsum,
                                 const float* __restrict__ expw,
                                 float* __restrict__ ctx,
                                 float* __restrict__ attn) {
    const int idx = blockIdx.x * 256 + threadIdx.x;
    if (idx < B_ * ENC_) {
        ctx[idx] = uctx[idx] / Zsum[idx >> 9];        // ENC_ = 512
    } else {
        const int i2 = idx - B_ * ENC_;
        attn[i2] = expw[i2] / Zsum[i2 >> 11];         // T_ = 2048
    }
}

// ---------------------------------------------------------------------------
extern "C" void kernel_launch(void* const* d_in, const int* in_sizes, int n_in,
                              void* d_out, int out_size, void* d_ws, size_t ws_size,
                              hipStream_t stream) {
    const float* dh  = (const float*)d_in[0];  // [64,512]
    const float* enc = (const float*)d_in[1];  // [64,2048,512]
    const float* Wa  = (const float*)d_in[2];  // [512,128]
    const float* ba  = (const float*)d_in[3];  // [128]
    const float* Wb  = (const float*)d_in[4];  // [512,128]
    const float* bb  = (const float*)d_in[5];  // [128]
    const float* Wv  = (const float*)d_in[6];  // [128,1]
    // d_in[7] = bv — cancels in softmax, unused.

    float* out      = (float*)d_out;
    float* ctx      = out;                 // [64,512]
    float* attn_out = out + (B_ * ENC_);   // [64,2048]

    float* ws   = (float*)d_ws;
    float* q    = ws;                              // 8192
    float* expw = ws + 8192;                       // 131072
    float* uctx = ws + 8192 + B_ * T_;             // 32768
    float* Zs   = uctx + B_ * ENC_;                // 64
    _Float16* whf = (_Float16*)(Zs + 64);          // 65536 halfs (128 KB)

    prep_kernel<<<225, 256, 0, stream>>>(dh, Wa, ba, bb, Wb, q, whf, uctx);
    score_ctx_kernel<<<(B_ * T_) / MBLK, 256, 0, stream>>>(enc, whf, q, Wv,
                                                           expw, uctx, Zs);
    normalize_kernel<<<(B_ * (ENC_ + T_)) / 256, 256, 0, stream>>>(uctx, Zs, expw,
                                                                   ctx, attn_out);
}